// Round 1
// baseline (1798.013 us; speedup 1.0000x reference)
//
#include <hip/hip_runtime.h>
#include <hip/hip_bf16.h>
#include <cstddef>

#define BB 4
#define CC 256
#define II 32
#define NN 4096
#define QT 32
#define MT 32

// ---------------- projection: out[b,o,n] = sum_c W[o,c]*x[b,c,n] + bias[o] ----
__global__ __launch_bounds__(256) void proj_kernel(const float* __restrict__ W,
    const float* __restrict__ bias, const float* __restrict__ x,
    float* __restrict__ out, int O) {
  __shared__ float wl[16 * 256];
  const int b = blockIdx.x, og = blockIdx.y;
  const int n = blockIdx.z * 256 + threadIdx.x;
  for (int e = threadIdx.x; e < 16 * 256; e += 256)
    wl[e] = W[(og * 16 + (e >> 8)) * 256 + (e & 255)];
  __syncthreads();
  float acc[16];
#pragma unroll
  for (int o = 0; o < 16; ++o) acc[o] = bias[og * 16 + o];
  const float* xp = x + (size_t)b * CC * NN + n;
  for (int c = 0; c < 256; c += 4) {
    float xv0 = xp[(size_t)(c + 0) * NN];
    float xv1 = xp[(size_t)(c + 1) * NN];
    float xv2 = xp[(size_t)(c + 2) * NN];
    float xv3 = xp[(size_t)(c + 3) * NN];
#pragma unroll
    for (int o = 0; o < 16; ++o) {
      float4 w4 = *(const float4*)&wl[o * 256 + c];
      acc[o] += w4.x * xv0 + w4.y * xv1 + w4.z * xv2 + w4.w * xv3;
    }
  }
#pragma unroll
  for (int o = 0; o < 16; ++o)
    out[((size_t)b * O + og * 16 + o) * NN + n] = acc[o];
}

// ---------------- fused flash attention -------------------------------------
// grid (B, N/QT), block 256.  LDS layout (floats):
//   ks  [32][33]   @ 0       (k tile, [dm][i])
//   vs  [32][260]  @ 1056    (v tile, [dm][c])
//   ps  [32][36]   @ 9376    (p tile, [dm][dn])
//   mrun[32] lrun[32] fs[32] @ 10528
__global__ __launch_bounds__(256, 3) void flash_kernel(
    const float* __restrict__ q, const float* __restrict__ k,
    const float* __restrict__ v, const float* __restrict__ x,
    const float* __restrict__ gamma, float* __restrict__ out) {
  __shared__ float smem[10624];
  float* ks = smem;
  float* vs = smem + 1056;
  float* ps = smem + 1056 + 8320;
  float* mrun = smem + 10528;
  float* lrun = smem + 10560;
  float* fs = smem + 10592;

  const int tid = threadIdx.x;
  const int b = blockIdx.x;
  const int n0 = blockIdx.y * QT;

  // s-phase identity: thread computes s[sdn][sdm0..sdm0+3]
  const int sdn = tid >> 3;
  const int sdm0 = (tid & 7) * 4;
  // acc-phase identity: thread owns acc[dnb..dnb+7][cb..cb+3]
  const int dnb = (tid >> 6) * 8;
  const int cb = (tid & 63) * 4;

  const float scale = 0.17677669529663687f;  // 1/sqrt(32)

  // q row for sdn into registers (pre-scaled)
  float qreg[II];
  {
    const float* qp = q + (size_t)b * II * NN + (n0 + sdn);
#pragma unroll
    for (int i = 0; i < II; ++i) qreg[i] = qp[(size_t)i * NN] * scale;
  }

  if (tid < QT) { mrun[tid] = -1e30f; lrun[tid] = 0.f; }
  float acc[8][4];
#pragma unroll
  for (int a = 0; a < 8; ++a)
#pragma unroll
    for (int cc = 0; cc < 4; ++cc) acc[a][cc] = 0.f;

  for (int m0 = 0; m0 < NN; m0 += MT) {
    __syncthreads();  // protect ks/vs/ps (and init) from previous phase
    // stage k tile: ks[dm][i] = k[b][i][m0+dm]
    {
      int e = tid;
#pragma unroll
      for (int j = 0; j < 4; ++j, e += 256) {
        int dm = e & 31, i = e >> 5;
        ks[dm * 33 + i] = k[((size_t)b * II + i) * NN + (m0 + dm)];
      }
    }
    // stage v tile: vs[dm][c] = v[b][c][m0+dm]
    {
      int e = tid;
#pragma unroll
      for (int j = 0; j < 32; ++j, e += 256) {
        int dm = e & 31, c = e >> 5;
        vs[dm * 260 + c] = v[((size_t)b * CC + c) * NN + (m0 + dm)];
      }
    }
    __syncthreads();

    // s-phase: 4 dots per thread
    float sv[4];
#pragma unroll
    for (int j = 0; j < 4; ++j) {
      int dm = sdm0 + j;
      float s = 0.f;
#pragma unroll
      for (int i = 0; i < II; ++i) s += qreg[i] * ks[dm * 33 + i];
      sv[j] = s;
    }
    float tmax = fmaxf(fmaxf(sv[0], sv[1]), fmaxf(sv[2], sv[3]));
#pragma unroll
    for (int mask = 1; mask <= 4; mask <<= 1)
      tmax = fmaxf(tmax, __shfl_xor(tmax, mask));
    float mold = mrun[sdn];
    float mnew = fmaxf(mold, tmax);
    float psum = 0.f;
#pragma unroll
    for (int j = 0; j < 4; ++j) {
      float p = __expf(sv[j] - mnew);
      ps[(sdm0 + j) * 36 + sdn] = p;
      psum += p;
    }
#pragma unroll
    for (int mask = 1; mask <= 4; mask <<= 1) psum += __shfl_xor(psum, mask);
    if ((tid & 7) == 0) {
      float f = __expf(mold - mnew);
      fs[sdn] = f;
      mrun[sdn] = mnew;
      lrun[sdn] = lrun[sdn] * f + psum;
    }
    __syncthreads();

    // acc-phase: rescale + PV accumulate
    float fv[8];
#pragma unroll
    for (int a = 0; a < 8; ++a) fv[a] = fs[dnb + a];
#pragma unroll
    for (int a = 0; a < 8; ++a)
#pragma unroll
      for (int cc = 0; cc < 4; ++cc) acc[a][cc] *= fv[a];
    for (int dm = 0; dm < MT; ++dm) {
      float4 v4 = *(const float4*)&vs[dm * 260 + cb];
      float4 p0 = *(const float4*)&ps[dm * 36 + dnb];
      float4 p1 = *(const float4*)&ps[dm * 36 + dnb + 4];
      float pa[8] = {p0.x, p0.y, p0.z, p0.w, p1.x, p1.y, p1.z, p1.w};
#pragma unroll
      for (int a = 0; a < 8; ++a) {
        acc[a][0] += pa[a] * v4.x;
        acc[a][1] += pa[a] * v4.y;
        acc[a][2] += pa[a] * v4.z;
        acc[a][3] += pa[a] * v4.w;
      }
    }
  }
  __syncthreads();

  // epilogue: normalize, transpose through LDS, coalesced write out = g*o + x
  float* ep = smem + 1056;  // [256][33], aliases vs/ps (dead now)
  float linv[8];
#pragma unroll
  for (int a = 0; a < 8; ++a) linv[a] = 1.0f / lrun[dnb + a];
#pragma unroll
  for (int a = 0; a < 8; ++a)
#pragma unroll
    for (int cc = 0; cc < 4; ++cc)
      ep[(cb + cc) * 33 + (dnb + a)] = acc[a][cc] * linv[a];
  __syncthreads();
  const float g = gamma[0];
  {
    int e = tid;
#pragma unroll
    for (int j = 0; j < 32; ++j, e += 256) {
      int dn = e & 31, c = e >> 5;
      size_t idx = ((size_t)b * CC + c) * NN + (n0 + dn);
      out[idx] = g * ep[c * 33 + dn] + x[idx];
    }
  }
}

extern "C" void kernel_launch(void* const* d_in, const int* in_sizes, int n_in,
                              void* d_out, int out_size, void* d_ws, size_t ws_size,
                              hipStream_t stream) {
  const float* x = (const float*)d_in[0];
  const float* Wq = (const float*)d_in[1];
  const float* bq = (const float*)d_in[2];
  const float* Wk = (const float*)d_in[3];
  const float* bk = (const float*)d_in[4];
  const float* Wv = (const float*)d_in[5];
  const float* bv = (const float*)d_in[6];
  const float* gamma = (const float*)d_in[7];
  float* out = (float*)d_out;

  float* ws = (float*)d_ws;
  float* qws = ws;                       // B*I*N   = 524288 floats
  float* kws = ws + (size_t)BB * II * NN;        // 524288 floats
  float* vws = kws + (size_t)BB * II * NN;       // B*C*N = 4194304 floats

  dim3 blk(256);
  proj_kernel<<<dim3(BB, II / 16, NN / 256), blk, 0, stream>>>(Wq, bq, x, qws, II);
  proj_kernel<<<dim3(BB, II / 16, NN / 256), blk, 0, stream>>>(Wk, bk, x, kws, II);
  proj_kernel<<<dim3(BB, CC / 16, NN / 256), blk, 0, stream>>>(Wv, bv, x, vws, CC);
  flash_kernel<<<dim3(BB, NN / QT), blk, 0, stream>>>(qws, kws, vws, x, gamma, out);
}

// Round 3
// 286.415 us; speedup vs baseline: 6.2776x; 6.2776x over previous
//
#include <hip/hip_runtime.h>
#include <hip/hip_bf16.h>
#include <cstddef>
#include <cstdint>

#define BB 4
#define CC 256
#define II 32
#define NN 4096

// 1/sqrt(32) * log2(e): fold softmax scale AND exp->exp2 conversion into q.
#define SCALE_Q 0.25505572751402893f

typedef __attribute__((ext_vector_type(8))) short bf16x8;
typedef __attribute__((ext_vector_type(16))) float f32x16;

static __device__ __forceinline__ ushort f2bf(float f) {
  __hip_bfloat16 h = __float2bfloat16(f);
  union { __hip_bfloat16 h; ushort u; } cv;
  cv.h = h;
  return cv.u;
}

static __device__ __forceinline__ int cvt_pk_bf16(float lo, float hi) {
  int d;
  asm("v_cvt_pk_bf16_f32 %0, %1, %2" : "=v"(d) : "v"(lo), "v"(hi));
  return d;
}
static __device__ __forceinline__ void perm32swap_i(int& a, int& b) {
  asm("v_permlane32_swap_b32 %0, %1" : "+v"(a), "+v"(b));
}
static __device__ __forceinline__ void perm32swap_f(float& a, float& b) {
  asm("v_permlane32_swap_b32 %0, %1" : "+v"(a), "+v"(b));
}
static __device__ __forceinline__ f32x16 zero16() {
  f32x16 z;
#pragma unroll
  for (int i = 0; i < 16; ++i) z[i] = 0.0f;
  return z;
}

// ---- proj q/k: out qT[b][n][i] (i contiguous), bf16, optional prescale ----
__global__ __launch_bounds__(256) void proj_qkT(const float* __restrict__ W,
    const float* __restrict__ bias, const float* __restrict__ x,
    __hip_bfloat16* __restrict__ outT, float prescale) {
  __shared__ float wl[16 * 256];
  const int b = blockIdx.x, og = blockIdx.y;
  const int n = blockIdx.z * 256 + threadIdx.x;
  for (int e = threadIdx.x; e < 16 * 256; e += 256)
    wl[e] = W[(og * 16 + (e >> 8)) * 256 + (e & 255)];
  __syncthreads();
  float acc[16];
#pragma unroll
  for (int o = 0; o < 16; ++o) acc[o] = bias[og * 16 + o];
  const float* xp = x + (size_t)b * CC * NN + n;
  for (int c = 0; c < 256; c += 4) {
    float xv0 = xp[(size_t)(c + 0) * NN];
    float xv1 = xp[(size_t)(c + 1) * NN];
    float xv2 = xp[(size_t)(c + 2) * NN];
    float xv3 = xp[(size_t)(c + 3) * NN];
#pragma unroll
    for (int o = 0; o < 16; ++o) {
      float4 w4 = *(const float4*)&wl[o * 256 + c];
      acc[o] += w4.x * xv0 + w4.y * xv1 + w4.z * xv2 + w4.w * xv3;
    }
  }
  union { ushort us[16]; int4 i4[2]; } pk;
#pragma unroll
  for (int o = 0; o < 16; ++o)
    pk.us[o] = f2bf(acc[o] * prescale);
  int4* dst = (int4*)(outT + ((size_t)b * NN + n) * II + og * 16);
  dst[0] = pk.i4[0];
  dst[1] = pk.i4[1];
}

// ---- proj v: out v[b][c][n] bf16 (n contiguous) ----
__global__ __launch_bounds__(256) void proj_v16(const float* __restrict__ W,
    const float* __restrict__ bias, const float* __restrict__ x,
    __hip_bfloat16* __restrict__ outv) {
  __shared__ float wl[16 * 256];
  const int b = blockIdx.x, og = blockIdx.y;
  const int n = blockIdx.z * 256 + threadIdx.x;
  for (int e = threadIdx.x; e < 16 * 256; e += 256)
    wl[e] = W[(og * 16 + (e >> 8)) * 256 + (e & 255)];
  __syncthreads();
  float acc[16];
#pragma unroll
  for (int o = 0; o < 16; ++o) acc[o] = bias[og * 16 + o];
  const float* xp = x + (size_t)b * CC * NN + n;
  for (int c = 0; c < 256; c += 4) {
    float xv0 = xp[(size_t)(c + 0) * NN];
    float xv1 = xp[(size_t)(c + 1) * NN];
    float xv2 = xp[(size_t)(c + 2) * NN];
    float xv3 = xp[(size_t)(c + 3) * NN];
#pragma unroll
    for (int o = 0; o < 16; ++o) {
      float4 w4 = *(const float4*)&wl[o * 256 + c];
      acc[o] += w4.x * xv0 + w4.y * xv1 + w4.z * xv2 + w4.w * xv3;
    }
  }
  union { ushort us[16]; int4 i4[2]; } pk;
#pragma unroll
  for (int o = 0; o < 16; ++o) pk.us[o] = f2bf(acc[o]);
  // write 16 channels for this n, strided by NN (scalar stores, coalesced in n)
#pragma unroll
  for (int o = 0; o < 16; ++o)
    ((ushort*)outv)[((size_t)b * CC + og * 16 + o) * NN + n] = pk.us[o];
}

// ---- flash attention, 1 wave = 32 q rows, MFMA 32x32x16 bf16 --------------
// grid (B, N/32), block 64.  No LDS, no barriers.
__global__ __launch_bounds__(64, 2) void flash_mfma(
    const __hip_bfloat16* __restrict__ qT, const __hip_bfloat16* __restrict__ kT,
    const __hip_bfloat16* __restrict__ v, const float* __restrict__ x,
    const float* __restrict__ gamma, float* __restrict__ out) {
  const int lane = threadIdx.x;
  const int l31 = lane & 31;
  const int h = lane >> 5;
  const int b = blockIdx.x;
  const int n0 = blockIdx.y * 32;

  // Q fragments (fixed for whole kernel): B-operand, col n = lane&31, k(i) = 8h+j
  const __hip_bfloat16* qrow = qT + ((size_t)b * NN + n0 + l31) * II + h * 8;
  const bf16x8 qf0 = *reinterpret_cast<const bf16x8*>(qrow);       // i 0..15
  const bf16x8 qf1 = *reinterpret_cast<const bf16x8*>(qrow + 16);  // i 16..31

  // K pointer: A-operand row m = lane&31, k(i) = 8h+j
  const __hip_bfloat16* kp = kT + ((size_t)b * NN + l31) * II + h * 8;
  // V row pointers: A-operand row c = ct*32 + lane&31, k(m) = 8h+j
  const __hip_bfloat16* vp = v + ((size_t)b * CC + l31) * NN + h * 8;

  f32x16 acc[8];
#pragma unroll
  for (int ct = 0; ct < 8; ++ct) acc[ct] = zero16();
  float m_run = -1e30f, l_run = 0.0f;

  for (int m0 = 0; m0 < NN; m0 += 64) {
    // ---- S^T = K^T . Q  (two 32x32 m-subtiles, k=32 in 2 steps) ----
    const bf16x8 kf00 = *reinterpret_cast<const bf16x8*>(kp);
    const bf16x8 kf01 = *reinterpret_cast<const bf16x8*>(kp + 16);
    const bf16x8 kf10 = *reinterpret_cast<const bf16x8*>(kp + 32 * II);
    const bf16x8 kf11 = *reinterpret_cast<const bf16x8*>(kp + 32 * II + 16);
    f32x16 st0 = zero16(), st1 = zero16();
    st0 = __builtin_amdgcn_mfma_f32_32x32x16_bf16(kf00, qf0, st0, 0, 0, 0);
    st1 = __builtin_amdgcn_mfma_f32_32x32x16_bf16(kf10, qf0, st1, 0, 0, 0);
    st0 = __builtin_amdgcn_mfma_f32_32x32x16_bf16(kf01, qf1, st0, 0, 0, 0);
    st1 = __builtin_amdgcn_mfma_f32_32x32x16_bf16(kf11, qf1, st1, 0, 0, 0);
    kp += 64 * II;

    // ---- row max over this tile (tree + one cross-half swap) ----
    float t[8];
#pragma unroll
    for (int r = 0; r < 8; ++r)
      t[r] = fmaxf(fmaxf(st0[r], st0[r + 8]), fmaxf(st1[r], st1[r + 8]));
    float mx = fmaxf(fmaxf(fmaxf(t[0], t[1]), fmaxf(t[2], t[3])),
                     fmaxf(fmaxf(t[4], t[5]), fmaxf(t[6], t[7])));
    float ma = mx, mb = mx;
    perm32swap_f(ma, mb);
    const float rowmax = fmaxf(ma, mb);

    // ---- deferred-max online softmax update (T13, thr=8 in log2 units) ----
    if (__any(rowmax > m_run + 8.0f)) {
      const float mnew = fmaxf(m_run, rowmax);
      const float f = exp2f(m_run - mnew);
#pragma unroll
      for (int ct = 0; ct < 8; ++ct)
#pragma unroll
        for (int r = 0; r < 16; ++r) acc[ct][r] *= f;
      l_run *= f;
      m_run = mnew;
    }

    // ---- p = exp2(s - m_run), row sum ----
#pragma unroll
    for (int r = 0; r < 16; ++r) st0[r] = exp2f(st0[r] - m_run);
#pragma unroll
    for (int r = 0; r < 16; ++r) st1[r] = exp2f(st1[r] - m_run);
    float s8[8];
#pragma unroll
    for (int r = 0; r < 8; ++r)
      s8[r] = (st0[r] + st0[r + 8]) + (st1[r] + st1[r + 8]);
    float ps = ((s8[0] + s8[1]) + (s8[2] + s8[3])) +
               ((s8[4] + s8[5]) + (s8[6] + s8[7]));
    float sa = ps, sb = ps;
    perm32swap_f(sa, sb);
    l_run += sa + sb;

    // ---- P -> bf16 B-fragments (cvt_pk + permlane32_swap, T12) ----
    union PF { int w[4]; bf16x8 v8; } pf[4];
    {
      int c0 = cvt_pk_bf16(st0[0], st0[1]), c1 = cvt_pk_bf16(st0[2], st0[3]);
      int c2 = cvt_pk_bf16(st0[4], st0[5]), c3 = cvt_pk_bf16(st0[6], st0[7]);
      perm32swap_i(c0, c2); perm32swap_i(c1, c3);
      pf[0].w[0] = c0; pf[0].w[1] = c1; pf[0].w[2] = c2; pf[0].w[3] = c3;
    }
    {
      int c0 = cvt_pk_bf16(st0[8], st0[9]), c1 = cvt_pk_bf16(st0[10], st0[11]);
      int c2 = cvt_pk_bf16(st0[12], st0[13]), c3 = cvt_pk_bf16(st0[14], st0[15]);
      perm32swap_i(c0, c2); perm32swap_i(c1, c3);
      pf[1].w[0] = c0; pf[1].w[1] = c1; pf[1].w[2] = c2; pf[1].w[3] = c3;
    }
    {
      int c0 = cvt_pk_bf16(st1[0], st1[1]), c1 = cvt_pk_bf16(st1[2], st1[3]);
      int c2 = cvt_pk_bf16(st1[4], st1[5]), c3 = cvt_pk_bf16(st1[6], st1[7]);
      perm32swap_i(c0, c2); perm32swap_i(c1, c3);
      pf[2].w[0] = c0; pf[2].w[1] = c1; pf[2].w[2] = c2; pf[2].w[3] = c3;
    }
    {
      int c0 = cvt_pk_bf16(st1[8], st1[9]), c1 = cvt_pk_bf16(st1[10], st1[11]);
      int c2 = cvt_pk_bf16(st1[12], st1[13]), c3 = cvt_pk_bf16(st1[14], st1[15]);
      perm32swap_i(c0, c2); perm32swap_i(c1, c3);
      pf[3].w[0] = c0; pf[3].w[1] = c1; pf[3].w[2] = c2; pf[3].w[3] = c3;
    }

    // ---- O += V . P^T : 4 k-steps x 8 c-tiles ----
#pragma unroll
    for (int ks = 0; ks < 4; ++ks) {
      bf16x8 vf[8];
#pragma unroll
      for (int ct = 0; ct < 8; ++ct)
        vf[ct] = *reinterpret_cast<const bf16x8*>(vp + (size_t)ct * 32 * NN + m0 + ks * 16);
#pragma unroll
      for (int ct = 0; ct < 8; ++ct)
        acc[ct] = __builtin_amdgcn_mfma_f32_32x32x16_bf16(vf[ct], pf[ks].v8, acc[ct], 0, 0, 0);
    }
  }

  // ---- epilogue: out = gamma * O/l + x ----
  const float linv = 1.0f / l_run;
  const float g = gamma[0];
#pragma unroll
  for (int ct = 0; ct < 8; ++ct) {
#pragma unroll
    for (int r = 0; r < 16; ++r) {
      const int c = ct * 32 + (r & 3) + 8 * (r >> 2) + 4 * h;
      const size_t idx = ((size_t)b * CC + c) * NN + n0 + l31;
      out[idx] = g * acc[ct][r] * linv + x[idx];
    }
  }
}

extern "C" void kernel_launch(void* const* d_in, const int* in_sizes, int n_in,
                              void* d_out, int out_size, void* d_ws, size_t ws_size,
                              hipStream_t stream) {
  const float* x = (const float*)d_in[0];
  const float* Wq = (const float*)d_in[1];
  const float* bq = (const float*)d_in[2];
  const float* Wk = (const float*)d_in[3];
  const float* bk = (const float*)d_in[4];
  const float* Wv = (const float*)d_in[5];
  const float* bv = (const float*)d_in[6];
  const float* gamma = (const float*)d_in[7];
  float* out = (float*)d_out;

  __hip_bfloat16* qT = (__hip_bfloat16*)d_ws;                 // B*N*32
  __hip_bfloat16* kTp = qT + (size_t)BB * NN * II;            // B*N*32
  __hip_bfloat16* vb = kTp + (size_t)BB * NN * II;            // B*C*N

  dim3 blk(256);
  proj_qkT<<<dim3(BB, II / 16, NN / 256), blk, 0, stream>>>(Wq, bq, x, qT, SCALE_Q);
  proj_qkT<<<dim3(BB, II / 16, NN / 256), blk, 0, stream>>>(Wk, bk, x, kTp, 1.0f);
  proj_v16<<<dim3(BB, CC / 16, NN / 256), blk, 0, stream>>>(Wv, bv, x, vb);
  flash_mfma<<<dim3(BB, NN / 32), dim3(64), 0, stream>>>(qT, kTp, vb, x, gamma, out);
}

// Round 4
// 180.744 us; speedup vs baseline: 9.9478x; 1.5846x over previous
//
#include <hip/hip_runtime.h>
#include <hip/hip_bf16.h>
#include <cstddef>
#include <cstdint>

#define BB 4
#define CC 256
#define II 32
#define NN 4096

// 1/sqrt(32) * log2(e): fold softmax scale AND exp->exp2 conversion into q.
#define SCALE_Q 0.25505572751402893f

typedef __attribute__((ext_vector_type(8))) short bf16x8;
typedef __attribute__((ext_vector_type(16))) float f32x16;

static __device__ __forceinline__ int cvt_pk_bf16(float lo, float hi) {
  int d;
  asm("v_cvt_pk_bf16_f32 %0, %1, %2" : "=v"(d) : "v"(lo), "v"(hi));
  return d;
}
static __device__ __forceinline__ void perm32swap_i(int& a, int& b) {
  asm("v_permlane32_swap_b32 %0, %1" : "+v"(a), "+v"(b));
}
static __device__ __forceinline__ void perm32swap_f(float& a, float& b) {
  asm("v_permlane32_swap_b32 %0, %1" : "+v"(a), "+v"(b));
}
static __device__ __forceinline__ f32x16 zero16() {
  f32x16 z;
#pragma unroll
  for (int i = 0; i < 16; ++i) z[i] = 0.0f;
  return z;
}
static __device__ __forceinline__ bf16x8 pack8(float f0, float f1, float f2,
    float f3, float f4, float f5, float f6, float f7) {
  union { int w[4]; bf16x8 v8; } u;
  u.w[0] = cvt_pk_bf16(f0, f1);
  u.w[1] = cvt_pk_bf16(f2, f3);
  u.w[2] = cvt_pk_bf16(f4, f5);
  u.w[3] = cvt_pk_bf16(f6, f7);
  return u.v8;
}

// ---- fused qkv projection, MFMA 32x32x16, 1 wave/block ---------------------
// grid (B, N/32, 5): og 0 -> q-tile + k-tile; og 1..4 -> v rows (og-1)*64..+63
// outputs: qT[b][n][i] bf16 (prescaled), kT[b][n][i] bf16, v[b][c][n] bf16
__global__ __launch_bounds__(64, 3) void proj_mfma(
    const float* __restrict__ Wq, const float* __restrict__ bq,
    const float* __restrict__ Wk, const float* __restrict__ bk,
    const float* __restrict__ Wv, const float* __restrict__ bv,
    const float* __restrict__ x,
    ushort* __restrict__ qT, ushort* __restrict__ kT, ushort* __restrict__ vb) {
  const int lane = threadIdx.x;
  const int l31 = lane & 31;
  const int h = lane >> 5;
  const int b = blockIdx.x;
  const int n0 = blockIdx.y * 32;
  const int og = blockIdx.z;

  const float* xb = x + (size_t)b * CC * NN + n0 + l31;
  const float* wr0 = (og == 0) ? (Wq + (size_t)l31 * CC)
                               : (Wv + (size_t)((og - 1) * 64 + l31) * CC);
  const float* wr1 = (og == 0) ? (Wk + (size_t)l31 * CC)
                               : (Wv + (size_t)((og - 1) * 64 + 32 + l31) * CC);

  f32x16 acc0 = zero16(), acc1 = zero16();
#pragma unroll 4
  for (int ks = 0; ks < 16; ++ks) {
    const int c = ks * 16 + h * 8;
    const float* xp = xb + (size_t)c * NN;
    bf16x8 xf = pack8(xp[0], xp[(size_t)1 * NN], xp[(size_t)2 * NN],
                      xp[(size_t)3 * NN], xp[(size_t)4 * NN], xp[(size_t)5 * NN],
                      xp[(size_t)6 * NN], xp[(size_t)7 * NN]);
    float4 wa = *(const float4*)(wr0 + c);
    float4 wb = *(const float4*)(wr0 + c + 4);
    bf16x8 wf0 = pack8(wa.x, wa.y, wa.z, wa.w, wb.x, wb.y, wb.z, wb.w);
    float4 wc = *(const float4*)(wr1 + c);
    float4 wd = *(const float4*)(wr1 + c + 4);
    bf16x8 wf1 = pack8(wc.x, wc.y, wc.z, wc.w, wd.x, wd.y, wd.z, wd.w);
    acc0 = __builtin_amdgcn_mfma_f32_32x32x16_bf16(wf0, xf, acc0, 0, 0, 0);
    acc1 = __builtin_amdgcn_mfma_f32_32x32x16_bf16(wf1, xf, acc1, 0, 0, 0);
  }

  if (og == 0) {
    // q (prescaled) and k, layout [n][i], i = row pattern
    ushort* qrow = qT + ((size_t)b * NN + n0 + l31) * II;
    ushort* krow = kT + ((size_t)b * NN + n0 + l31) * II;
#pragma unroll
    for (int r = 0; r < 16; ++r) {
      const int i = (r & 3) + 8 * (r >> 2) + 4 * h;
      union { __hip_bfloat16 h2; ushort u; } cq, ck;
      cq.h2 = __float2bfloat16((acc0[r] + bq[i]) * SCALE_Q);
      ck.h2 = __float2bfloat16(acc1[r] + bk[i]);
      qrow[i] = cq.u;
      krow[i] = ck.u;
    }
  } else {
#pragma unroll
    for (int r = 0; r < 16; ++r) {
      const int rp = (r & 3) + 8 * (r >> 2) + 4 * h;
      const int c0 = (og - 1) * 64 + rp;
      const int c1 = c0 + 32;
      union { __hip_bfloat16 h2; ushort u; } v0, v1;
      v0.h2 = __float2bfloat16(acc0[r] + bv[c0]);
      v1.h2 = __float2bfloat16(acc1[r] + bv[c1]);
      vb[((size_t)b * CC + c0) * NN + n0 + l31] = v0.u;
      vb[((size_t)b * CC + c1) * NN + n0 + l31] = v1.u;
    }
  }
}

// ---- flash attention: 4 waves/block, c-split PV, MFMA 32x32x16 bf16 --------
// grid (B, N/32), block 256. Wave w owns output channels [w*64, w*64+64).
// QK^T + softmax duplicated per wave (cheap); no LDS, no barriers.
__global__ __launch_bounds__(256, 2) void flash_mfma(
    const __hip_bfloat16* __restrict__ qT, const __hip_bfloat16* __restrict__ kT,
    const __hip_bfloat16* __restrict__ v, const float* __restrict__ x,
    const float* __restrict__ gamma, float* __restrict__ out) {
  const int tid = threadIdx.x;
  const int lane = tid & 63;
  const int w = tid >> 6;
  const int l31 = lane & 31;
  const int h = lane >> 5;
  const int b = blockIdx.x;
  const int n0 = blockIdx.y * 32;

  // Q fragments: B-operand, col n = l31, k(i) = 8h+j
  const __hip_bfloat16* qrow = qT + ((size_t)b * NN + n0 + l31) * II + h * 8;
  const bf16x8 qf0 = *reinterpret_cast<const bf16x8*>(qrow);
  const bf16x8 qf1 = *reinterpret_cast<const bf16x8*>(qrow + 16);

  // K pointer: A-operand row m = l31, k(i) = 8h+j
  const __hip_bfloat16* kp = kT + ((size_t)b * NN + l31) * II + h * 8;
  // V pointer: A-operand row c = w*64 + ct*32 + l31, k(m) = 8h+j
  const __hip_bfloat16* vp = v + ((size_t)b * CC + w * 64 + l31) * NN + h * 8;

  f32x16 acc0 = zero16(), acc1 = zero16();
  float m_run = -1e30f, l_run = 0.0f;

  for (int m0 = 0; m0 < NN; m0 += 64) {
    // ---- S^T = K^T . Q ----
    const bf16x8 kf00 = *reinterpret_cast<const bf16x8*>(kp);
    const bf16x8 kf01 = *reinterpret_cast<const bf16x8*>(kp + 16);
    const bf16x8 kf10 = *reinterpret_cast<const bf16x8*>(kp + 32 * II);
    const bf16x8 kf11 = *reinterpret_cast<const bf16x8*>(kp + 32 * II + 16);
    f32x16 st0 = zero16(), st1 = zero16();
    st0 = __builtin_amdgcn_mfma_f32_32x32x16_bf16(kf00, qf0, st0, 0, 0, 0);
    st1 = __builtin_amdgcn_mfma_f32_32x32x16_bf16(kf10, qf0, st1, 0, 0, 0);
    st0 = __builtin_amdgcn_mfma_f32_32x32x16_bf16(kf01, qf1, st0, 0, 0, 0);
    st1 = __builtin_amdgcn_mfma_f32_32x32x16_bf16(kf11, qf1, st1, 0, 0, 0);
    kp += 64 * II;

    // ---- row max ----
    float t[8];
#pragma unroll
    for (int r = 0; r < 8; ++r)
      t[r] = fmaxf(fmaxf(st0[r], st0[r + 8]), fmaxf(st1[r], st1[r + 8]));
    float mx = fmaxf(fmaxf(fmaxf(t[0], t[1]), fmaxf(t[2], t[3])),
                     fmaxf(fmaxf(t[4], t[5]), fmaxf(t[6], t[7])));
    float ma = mx, mb = mx;
    perm32swap_f(ma, mb);
    const float rowmax = fmaxf(ma, mb);

    // ---- deferred-max online softmax update ----
    if (__any(rowmax > m_run + 8.0f)) {
      const float mnew = fmaxf(m_run, rowmax);
      const float f = exp2f(m_run - mnew);
#pragma unroll
      for (int r = 0; r < 16; ++r) { acc0[r] *= f; acc1[r] *= f; }
      l_run *= f;
      m_run = mnew;
    }

    // ---- p = exp2(s - m), row sum ----
#pragma unroll
    for (int r = 0; r < 16; ++r) st0[r] = exp2f(st0[r] - m_run);
#pragma unroll
    for (int r = 0; r < 16; ++r) st1[r] = exp2f(st1[r] - m_run);
    float s8[8];
#pragma unroll
    for (int r = 0; r < 8; ++r)
      s8[r] = (st0[r] + st0[r + 8]) + (st1[r] + st1[r + 8]);
    float ps = ((s8[0] + s8[1]) + (s8[2] + s8[3])) +
               ((s8[4] + s8[5]) + (s8[6] + s8[7]));
    float sa = ps, sb = ps;
    perm32swap_f(sa, sb);
    l_run += sa + sb;

    // ---- P -> bf16 B-fragments (cvt_pk + permlane32_swap) ----
    union PF { int w4[4]; bf16x8 v8; } pf[4];
    {
      int c0 = cvt_pk_bf16(st0[0], st0[1]), c1 = cvt_pk_bf16(st0[2], st0[3]);
      int c2 = cvt_pk_bf16(st0[4], st0[5]), c3 = cvt_pk_bf16(st0[6], st0[7]);
      perm32swap_i(c0, c2); perm32swap_i(c1, c3);
      pf[0].w4[0] = c0; pf[0].w4[1] = c1; pf[0].w4[2] = c2; pf[0].w4[3] = c3;
    }
    {
      int c0 = cvt_pk_bf16(st0[8], st0[9]), c1 = cvt_pk_bf16(st0[10], st0[11]);
      int c2 = cvt_pk_bf16(st0[12], st0[13]), c3 = cvt_pk_bf16(st0[14], st0[15]);
      perm32swap_i(c0, c2); perm32swap_i(c1, c3);
      pf[1].w4[0] = c0; pf[1].w4[1] = c1; pf[1].w4[2] = c2; pf[1].w4[3] = c3;
    }
    {
      int c0 = cvt_pk_bf16(st1[0], st1[1]), c1 = cvt_pk_bf16(st1[2], st1[3]);
      int c2 = cvt_pk_bf16(st1[4], st1[5]), c3 = cvt_pk_bf16(st1[6], st1[7]);
      perm32swap_i(c0, c2); perm32swap_i(c1, c3);
      pf[2].w4[0] = c0; pf[2].w4[1] = c1; pf[2].w4[2] = c2; pf[2].w4[3] = c3;
    }
    {
      int c0 = cvt_pk_bf16(st1[8], st1[9]), c1 = cvt_pk_bf16(st1[10], st1[11]);
      int c2 = cvt_pk_bf16(st1[12], st1[13]), c3 = cvt_pk_bf16(st1[14], st1[15]);
      perm32swap_i(c0, c2); perm32swap_i(c1, c3);
      pf[3].w4[0] = c0; pf[3].w4[1] = c1; pf[3].w4[2] = c2; pf[3].w4[3] = c3;
    }

    // ---- O += V . P^T : 4 k-steps x 2 c-tiles (this wave's channels) ----
#pragma unroll
    for (int ksi = 0; ksi < 4; ++ksi) {
      const bf16x8 vf0 = *reinterpret_cast<const bf16x8*>(vp + m0 + ksi * 16);
      const bf16x8 vf1 = *reinterpret_cast<const bf16x8*>(vp + (size_t)32 * NN + m0 + ksi * 16);
      acc0 = __builtin_amdgcn_mfma_f32_32x32x16_bf16(vf0, pf[ksi].v8, acc0, 0, 0, 0);
      acc1 = __builtin_amdgcn_mfma_f32_32x32x16_bf16(vf1, pf[ksi].v8, acc1, 0, 0, 0);
    }
  }

  // ---- epilogue: out = gamma * O/l + x ----
  const float linv = 1.0f / l_run;
  const float g = gamma[0];
#pragma unroll
  for (int r = 0; r < 16; ++r) {
    const int rp = (r & 3) + 8 * (r >> 2) + 4 * h;
    const int c0 = w * 64 + rp;
    const size_t i0 = ((size_t)b * CC + c0) * NN + n0 + l31;
    const size_t i1 = ((size_t)b * CC + c0 + 32) * NN + n0 + l31;
    out[i0] = g * acc0[r] * linv + x[i0];
    out[i1] = g * acc1[r] * linv + x[i1];
  }
}

extern "C" void kernel_launch(void* const* d_in, const int* in_sizes, int n_in,
                              void* d_out, int out_size, void* d_ws, size_t ws_size,
                              hipStream_t stream) {
  const float* x = (const float*)d_in[0];
  const float* Wq = (const float*)d_in[1];
  const float* bq = (const float*)d_in[2];
  const float* Wk = (const float*)d_in[3];
  const float* bk = (const float*)d_in[4];
  const float* Wv = (const float*)d_in[5];
  const float* bv = (const float*)d_in[6];
  const float* gamma = (const float*)d_in[7];
  float* out = (float*)d_out;

  ushort* qT = (ushort*)d_ws;                       // B*N*32
  ushort* kT = qT + (size_t)BB * NN * II;           // B*N*32
  ushort* vb = kT + (size_t)BB * NN * II;           // B*C*N

  proj_mfma<<<dim3(BB, NN / 32, 5), dim3(64), 0, stream>>>(
      Wq, bq, Wk, bk, Wv, bv, x, qT, kT, vb);
  flash_mfma<<<dim3(BB, NN / 32), dim3(256), 0, stream>>>(
      (const __hip_bfloat16*)qT, (const __hip_bfloat16*)kT,
      (const __hip_bfloat16*)vb, x, gamma, out);
}

// Round 5
// 166.913 us; speedup vs baseline: 10.7721x; 1.0829x over previous
//
#include <hip/hip_runtime.h>
#include <hip/hip_bf16.h>
#include <cstddef>
#include <cstdint>

#define BB 4
#define CC 256
#define II 32
#define NN 4096

// 1/sqrt(32) * log2(e): fold softmax scale AND exp->exp2 conversion into q.
#define SCALE_Q 0.25505572751402893f

typedef __attribute__((ext_vector_type(8))) short bf16x8;
typedef __attribute__((ext_vector_type(16))) float f32x16;

static __device__ __forceinline__ int cvt_pk_bf16(float lo, float hi) {
  int d;
  asm("v_cvt_pk_bf16_f32 %0, %1, %2" : "=v"(d) : "v"(lo), "v"(hi));
  return d;
}
static __device__ __forceinline__ void perm32swap_i(int& a, int& b) {
  asm("v_permlane32_swap_b32 %0, %1" : "+v"(a), "+v"(b));
}
static __device__ __forceinline__ void perm32swap_f(float& a, float& b) {
  asm("v_permlane32_swap_b32 %0, %1" : "+v"(a), "+v"(b));
}
static __device__ __forceinline__ f32x16 zero16() {
  f32x16 z;
#pragma unroll
  for (int i = 0; i < 16; ++i) z[i] = 0.0f;
  return z;
}
static __device__ __forceinline__ bf16x8 pack8(float f0, float f1, float f2,
    float f3, float f4, float f5, float f6, float f7) {
  union { int w[4]; bf16x8 v8; } u;
  u.w[0] = cvt_pk_bf16(f0, f1);
  u.w[1] = cvt_pk_bf16(f2, f3);
  u.w[2] = cvt_pk_bf16(f4, f5);
  u.w[3] = cvt_pk_bf16(f6, f7);
  return u.v8;
}

// ---- fused qkv projection, MFMA 32x32x16, 1 wave/block ---------------------
// grid (B, N/32, 5): og 0 -> q-tile + k-tile; og 1..4 -> v rows (og-1)*64..+63
__global__ __launch_bounds__(64, 3) void proj_mfma(
    const float* __restrict__ Wq, const float* __restrict__ bq,
    const float* __restrict__ Wk, const float* __restrict__ bk,
    const float* __restrict__ Wv, const float* __restrict__ bv,
    const float* __restrict__ x,
    ushort* __restrict__ qT, ushort* __restrict__ kT, ushort* __restrict__ vb) {
  const int lane = threadIdx.x;
  const int l31 = lane & 31;
  const int h = lane >> 5;
  const int b = blockIdx.x;
  const int n0 = blockIdx.y * 32;
  const int og = blockIdx.z;

  const float* xb = x + (size_t)b * CC * NN + n0 + l31;
  const float* wr0 = (og == 0) ? (Wq + (size_t)l31 * CC)
                               : (Wv + (size_t)((og - 1) * 64 + l31) * CC);
  const float* wr1 = (og == 0) ? (Wk + (size_t)l31 * CC)
                               : (Wv + (size_t)((og - 1) * 64 + 32 + l31) * CC);

  f32x16 acc0 = zero16(), acc1 = zero16();
#pragma unroll 4
  for (int ks = 0; ks < 16; ++ks) {
    const int c = ks * 16 + h * 8;
    const float* xp = xb + (size_t)c * NN;
    bf16x8 xf = pack8(xp[0], xp[(size_t)1 * NN], xp[(size_t)2 * NN],
                      xp[(size_t)3 * NN], xp[(size_t)4 * NN], xp[(size_t)5 * NN],
                      xp[(size_t)6 * NN], xp[(size_t)7 * NN]);
    float4 wa = *(const float4*)(wr0 + c);
    float4 wb = *(const float4*)(wr0 + c + 4);
    bf16x8 wf0 = pack8(wa.x, wa.y, wa.z, wa.w, wb.x, wb.y, wb.z, wb.w);
    float4 wc = *(const float4*)(wr1 + c);
    float4 wd = *(const float4*)(wr1 + c + 4);
    bf16x8 wf1 = pack8(wc.x, wc.y, wc.z, wc.w, wd.x, wd.y, wd.z, wd.w);
    acc0 = __builtin_amdgcn_mfma_f32_32x32x16_bf16(wf0, xf, acc0, 0, 0, 0);
    acc1 = __builtin_amdgcn_mfma_f32_32x32x16_bf16(wf1, xf, acc1, 0, 0, 0);
  }

  if (og == 0) {
    ushort* qrow = qT + ((size_t)b * NN + n0 + l31) * II;
    ushort* krow = kT + ((size_t)b * NN + n0 + l31) * II;
#pragma unroll
    for (int r = 0; r < 16; ++r) {
      const int i = (r & 3) + 8 * (r >> 2) + 4 * h;
      union { __hip_bfloat16 h2; ushort u; } cq, ck;
      cq.h2 = __float2bfloat16((acc0[r] + bq[i]) * SCALE_Q);
      ck.h2 = __float2bfloat16(acc1[r] + bk[i]);
      qrow[i] = cq.u;
      krow[i] = ck.u;
    }
  } else {
#pragma unroll
    for (int r = 0; r < 16; ++r) {
      const int rp = (r & 3) + 8 * (r >> 2) + 4 * h;
      const int c0 = (og - 1) * 64 + rp;
      const int c1 = c0 + 32;
      union { __hip_bfloat16 h2; ushort u; } v0, v1;
      v0.h2 = __float2bfloat16(acc0[r] + bv[c0]);
      v1.h2 = __float2bfloat16(acc1[r] + bv[c1]);
      vb[((size_t)b * CC + c0) * NN + n0 + l31] = v0.u;
      vb[((size_t)b * CC + c1) * NN + n0 + l31] = v1.u;
    }
  }
}

// ---- flash attention: 4 waves/block, KEY-split, MFMA 32x32x16 bf16 ---------
// grid (B, N/32), block 256. Wave w owns keys [w*1024, (w+1)*1024) with its
// own online softmax (full-C accumulator); in-LDS flash-decoding combine.
__global__ __launch_bounds__(256, 2) void flash_mfma(
    const __hip_bfloat16* __restrict__ qT, const __hip_bfloat16* __restrict__ kT,
    const __hip_bfloat16* __restrict__ v, const float* __restrict__ x,
    const float* __restrict__ gamma, float* __restrict__ out) {
  __shared__ float smem[17152];  // B0[256*33] B1[256*33] ml[128] ll[128]
  float* B0 = smem;
  float* B1 = smem + 8448;
  float* ml = smem + 16896;
  float* ll = smem + 17024;

  const int tid = threadIdx.x;
  const int lane = tid & 63;
  const int w = tid >> 6;
  const int l31 = lane & 31;
  const int h = lane >> 5;
  const int b = blockIdx.x;
  const int n0 = blockIdx.y * 32;
  const int kbase = w * (NN / 4);

  // Q fragments: B-operand, col n = l31, k(i) = 8h+j
  const __hip_bfloat16* qrow = qT + ((size_t)b * NN + n0 + l31) * II + h * 8;
  const bf16x8 qf0 = *reinterpret_cast<const bf16x8*>(qrow);
  const bf16x8 qf1 = *reinterpret_cast<const bf16x8*>(qrow + 16);

  // K pointer: A-operand row m = kbase + l31, k(i) = 8h+j
  const __hip_bfloat16* kp = kT + ((size_t)b * NN + kbase + l31) * II + h * 8;
  // V pointer: A-operand row c = ct*32 + l31, k(m) = 8h+j
  const __hip_bfloat16* vp = v + ((size_t)b * CC + l31) * NN + h * 8;

  f32x16 acc[8];
#pragma unroll
  for (int ct = 0; ct < 8; ++ct) acc[ct] = zero16();
  float m_run = -1e30f, l_run = 0.0f;

  for (int m0 = 0; m0 < NN / 4; m0 += 64) {
    const int kabs = kbase + m0;
    // ---- S^T = K^T . Q ----
    const bf16x8 kf00 = *reinterpret_cast<const bf16x8*>(kp);
    const bf16x8 kf01 = *reinterpret_cast<const bf16x8*>(kp + 16);
    const bf16x8 kf10 = *reinterpret_cast<const bf16x8*>(kp + 32 * II);
    const bf16x8 kf11 = *reinterpret_cast<const bf16x8*>(kp + 32 * II + 16);
    f32x16 st0 = zero16(), st1 = zero16();
    st0 = __builtin_amdgcn_mfma_f32_32x32x16_bf16(kf00, qf0, st0, 0, 0, 0);
    st1 = __builtin_amdgcn_mfma_f32_32x32x16_bf16(kf10, qf0, st1, 0, 0, 0);
    st0 = __builtin_amdgcn_mfma_f32_32x32x16_bf16(kf01, qf1, st0, 0, 0, 0);
    st1 = __builtin_amdgcn_mfma_f32_32x32x16_bf16(kf11, qf1, st1, 0, 0, 0);
    kp += 64 * II;

    // ---- row max ----
    float t[8];
#pragma unroll
    for (int r = 0; r < 8; ++r)
      t[r] = fmaxf(fmaxf(st0[r], st0[r + 8]), fmaxf(st1[r], st1[r + 8]));
    float mx = fmaxf(fmaxf(fmaxf(t[0], t[1]), fmaxf(t[2], t[3])),
                     fmaxf(fmaxf(t[4], t[5]), fmaxf(t[6], t[7])));
    float ma = mx, mb = mx;
    perm32swap_f(ma, mb);
    const float rowmax = fmaxf(ma, mb);

    // ---- deferred-max online softmax update ----
    if (__any(rowmax > m_run + 8.0f)) {
      const float mnew = fmaxf(m_run, rowmax);
      const float f = exp2f(m_run - mnew);
#pragma unroll
      for (int ct = 0; ct < 8; ++ct)
#pragma unroll
        for (int r = 0; r < 16; ++r) acc[ct][r] *= f;
      l_run *= f;
      m_run = mnew;
    }

    // ---- p = exp2(s - m), row sum ----
#pragma unroll
    for (int r = 0; r < 16; ++r) st0[r] = exp2f(st0[r] - m_run);
#pragma unroll
    for (int r = 0; r < 16; ++r) st1[r] = exp2f(st1[r] - m_run);
    float s8[8];
#pragma unroll
    for (int r = 0; r < 8; ++r)
      s8[r] = (st0[r] + st0[r + 8]) + (st1[r] + st1[r + 8]);
    float ps = ((s8[0] + s8[1]) + (s8[2] + s8[3])) +
               ((s8[4] + s8[5]) + (s8[6] + s8[7]));
    float sa = ps, sb = ps;
    perm32swap_f(sa, sb);
    l_run += sa + sb;

    // ---- P -> bf16 B-fragments (cvt_pk + permlane32_swap) ----
    union PF { int w4[4]; bf16x8 v8; } pf[4];
    {
      int c0 = cvt_pk_bf16(st0[0], st0[1]), c1 = cvt_pk_bf16(st0[2], st0[3]);
      int c2 = cvt_pk_bf16(st0[4], st0[5]), c3 = cvt_pk_bf16(st0[6], st0[7]);
      perm32swap_i(c0, c2); perm32swap_i(c1, c3);
      pf[0].w4[0] = c0; pf[0].w4[1] = c1; pf[0].w4[2] = c2; pf[0].w4[3] = c3;
    }
    {
      int c0 = cvt_pk_bf16(st0[8], st0[9]), c1 = cvt_pk_bf16(st0[10], st0[11]);
      int c2 = cvt_pk_bf16(st0[12], st0[13]), c3 = cvt_pk_bf16(st0[14], st0[15]);
      perm32swap_i(c0, c2); perm32swap_i(c1, c3);
      pf[1].w4[0] = c0; pf[1].w4[1] = c1; pf[1].w4[2] = c2; pf[1].w4[3] = c3;
    }
    {
      int c0 = cvt_pk_bf16(st1[0], st1[1]), c1 = cvt_pk_bf16(st1[2], st1[3]);
      int c2 = cvt_pk_bf16(st1[4], st1[5]), c3 = cvt_pk_bf16(st1[6], st1[7]);
      perm32swap_i(c0, c2); perm32swap_i(c1, c3);
      pf[2].w4[0] = c0; pf[2].w4[1] = c1; pf[2].w4[2] = c2; pf[2].w4[3] = c3;
    }
    {
      int c0 = cvt_pk_bf16(st1[8], st1[9]), c1 = cvt_pk_bf16(st1[10], st1[11]);
      int c2 = cvt_pk_bf16(st1[12], st1[13]), c3 = cvt_pk_bf16(st1[14], st1[15]);
      perm32swap_i(c0, c2); perm32swap_i(c1, c3);
      pf[3].w4[0] = c0; pf[3].w4[1] = c1; pf[3].w4[2] = c2; pf[3].w4[3] = c3;
    }

    // ---- O += V . P^T : 4 k-steps x 8 c-tiles ----
#pragma unroll
    for (int ksi = 0; ksi < 4; ++ksi) {
      bf16x8 vf[8];
#pragma unroll
      for (int ct = 0; ct < 8; ++ct)
        vf[ct] = *reinterpret_cast<const bf16x8*>(
            vp + (size_t)ct * 32 * NN + kabs + ksi * 16);
#pragma unroll
      for (int ct = 0; ct < 8; ++ct)
        acc[ct] = __builtin_amdgcn_mfma_f32_32x32x16_bf16(vf[ct], pf[ksi].v8, acc[ct], 0, 0, 0);
    }
  }

  // ---- flash-decoding combine across the 4 key-chunks (in LDS) ----
  if (h == 0) { ml[w * 32 + l31] = m_run; ll[w * 32 + l31] = l_run; }
  __syncthreads();
  const int q = tid & 31;  // == l31
  const float m0_ = ml[q], m1_ = ml[32 + q], m2_ = ml[64 + q], m3_ = ml[96 + q];
  const float mt = fmaxf(fmaxf(m0_, m1_), fmaxf(m2_, m3_));
  const float f0 = exp2f(m0_ - mt), f1 = exp2f(m1_ - mt);
  const float f2 = exp2f(m2_ - mt), f3 = exp2f(m3_ - mt);
  const float lt = f0 * ll[q] + f1 * ll[32 + q] + f2 * ll[64 + q] + f3 * ll[96 + q];
  const float fmy = (w == 0) ? f0 : (w == 1) ? f1 : (w == 2) ? f2 : f3;

  if (w < 2) {
    float* Bd = (w == 0) ? B0 : B1;
#pragma unroll
    for (int ct = 0; ct < 8; ++ct)
#pragma unroll
      for (int r = 0; r < 16; ++r) {
        const int c = ct * 32 + (r & 3) + 8 * (r >> 2) + 4 * h;
        Bd[c * 33 + l31] = fmy * acc[ct][r];
      }
  }
  __syncthreads();
  if (w >= 2) {
    float* Bd = (w == 2) ? B0 : B1;
#pragma unroll
    for (int ct = 0; ct < 8; ++ct)
#pragma unroll
      for (int r = 0; r < 16; ++r) {
        const int c = ct * 32 + (r & 3) + 8 * (r >> 2) + 4 * h;
        Bd[c * 33 + l31] += fmy * acc[ct][r];
      }
  }
  __syncthreads();

  // ---- epilogue: out = gamma * O/l + x (coalesced) ----
  const float g = gamma[0];
  const float linv = 1.0f / lt;
#pragma unroll
  for (int rep = 0; rep < 32; ++rep) {
    const int flat = rep * 256 + tid;
    const int c = flat >> 5;
    const float o = B0[c * 33 + q] + B1[c * 33 + q];
    const size_t idx = ((size_t)b * CC + c) * NN + n0 + q;
    out[idx] = g * o * linv + x[idx];
  }
}

extern "C" void kernel_launch(void* const* d_in, const int* in_sizes, int n_in,
                              void* d_out, int out_size, void* d_ws, size_t ws_size,
                              hipStream_t stream) {
  const float* x = (const float*)d_in[0];
  const float* Wq = (const float*)d_in[1];
  const float* bq = (const float*)d_in[2];
  const float* Wk = (const float*)d_in[3];
  const float* bk = (const float*)d_in[4];
  const float* Wv = (const float*)d_in[5];
  const float* bv = (const float*)d_in[6];
  const float* gamma = (const float*)d_in[7];
  float* out = (float*)d_out;

  ushort* qT = (ushort*)d_ws;                       // B*N*32
  ushort* kT = qT + (size_t)BB * NN * II;           // B*N*32
  ushort* vb = kT + (size_t)BB * NN * II;           // B*C*N

  proj_mfma<<<dim3(BB, NN / 32, 5), dim3(64), 0, stream>>>(
      Wq, bq, Wk, bk, Wv, bv, x, qT, kT, vb);
  flash_mfma<<<dim3(BB, NN / 32), dim3(256), 0, stream>>>(
      (const __hip_bfloat16*)qT, (const __hip_bfloat16*)kT,
      (const __hip_bfloat16*)vb, x, gamma, out);
}

// Round 6
// 88.071 us; speedup vs baseline: 20.4155x; 1.8952x over previous
//
#include <hip/hip_runtime.h>
#include <hip/hip_bf16.h>
#include <cstddef>
#include <cstdint>

#define BB 4
#define CC 256
#define II 32
#define NN 4096

// 1/sqrt(32) * log2(e): fold softmax scale AND exp->exp2 conversion into q.
#define SCALE_Q 0.25505572751402893f

typedef __attribute__((ext_vector_type(8))) short bf16x8;
typedef __attribute__((ext_vector_type(16))) float f32x16;

static __device__ __forceinline__ int cvt_pk_bf16(float lo, float hi) {
  int d;
  asm("v_cvt_pk_bf16_f32 %0, %1, %2" : "=v"(d) : "v"(lo), "v"(hi));
  return d;
}
static __device__ __forceinline__ void perm32swap_i(int& a, int& b) {
  asm("v_permlane32_swap_b32 %0, %1" : "+v"(a), "+v"(b));
}
static __device__ __forceinline__ void perm32swap_f(float& a, float& b) {
  asm("v_permlane32_swap_b32 %0, %1" : "+v"(a), "+v"(b));
}
static __device__ __forceinline__ f32x16 zero16() {
  f32x16 z;
#pragma unroll
  for (int i = 0; i < 16; ++i) z[i] = 0.0f;
  return z;
}
static __device__ __forceinline__ bf16x8 pack8(float f0, float f1, float f2,
    float f3, float f4, float f5, float f6, float f7) {
  union { int w[4]; bf16x8 v8; } u;
  u.w[0] = cvt_pk_bf16(f0, f1);
  u.w[1] = cvt_pk_bf16(f2, f3);
  u.w[2] = cvt_pk_bf16(f4, f5);
  u.w[3] = cvt_pk_bf16(f6, f7);
  return u.v8;
}
static __device__ __forceinline__ ushort f2bfu(float f) {
  union { __hip_bfloat16 h; ushort u; } cv;
  cv.h = __float2bfloat16(f);
  return cv.u;
}

// Tiled fragment layouts (all ushort/bf16):
//  qT/kT: [b][mt=n/32][frag=i/16][p]  p = 256*((i>>3)&1) + 8*(n&31) + (i&7)
//         chunk of 512; a wave loads p = lane*8 .. +7 contiguously (1KB).
//  vT:    [b][nt=n/16][ct=c/32][p]    p = 256*((n>>3)&1) + 8*(c&31) + (n&7)

// ---- fused qkv projection, MFMA 32x32x16, 1 wave/block ---------------------
// grid (B, N/32, 5): og 0 -> q-tile + k-tile; og 1..4 -> v rows (og-1)*64..+63
__global__ __launch_bounds__(64, 3) void proj_mfma(
    const float* __restrict__ Wq, const float* __restrict__ bq,
    const float* __restrict__ Wk, const float* __restrict__ bk,
    const float* __restrict__ Wv, const float* __restrict__ bv,
    const float* __restrict__ x,
    ushort* __restrict__ qT, ushort* __restrict__ kT, ushort* __restrict__ vT) {
  const int lane = threadIdx.x;
  const int l31 = lane & 31;
  const int h = lane >> 5;
  const int b = blockIdx.x;
  const int n0 = blockIdx.y * 32;
  const int og = blockIdx.z;

  const float* xb = x + (size_t)b * CC * NN + n0 + l31;
  const float* wr0 = (og == 0) ? (Wq + (size_t)l31 * CC)
                               : (Wv + (size_t)((og - 1) * 64 + l31) * CC);
  const float* wr1 = (og == 0) ? (Wk + (size_t)l31 * CC)
                               : (Wv + (size_t)((og - 1) * 64 + 32 + l31) * CC);

  f32x16 acc0 = zero16(), acc1 = zero16();
#pragma unroll 4
  for (int ks = 0; ks < 16; ++ks) {
    const int c = ks * 16 + h * 8;
    const float* xp = xb + (size_t)c * NN;
    bf16x8 xf = pack8(xp[0], xp[(size_t)1 * NN], xp[(size_t)2 * NN],
                      xp[(size_t)3 * NN], xp[(size_t)4 * NN], xp[(size_t)5 * NN],
                      xp[(size_t)6 * NN], xp[(size_t)7 * NN]);
    float4 wa = *(const float4*)(wr0 + c);
    float4 wb = *(const float4*)(wr0 + c + 4);
    bf16x8 wf0 = pack8(wa.x, wa.y, wa.z, wa.w, wb.x, wb.y, wb.z, wb.w);
    float4 wc = *(const float4*)(wr1 + c);
    float4 wd = *(const float4*)(wr1 + c + 4);
    bf16x8 wf1 = pack8(wc.x, wc.y, wc.z, wc.w, wd.x, wd.y, wd.z, wd.w);
    acc0 = __builtin_amdgcn_mfma_f32_32x32x16_bf16(wf0, xf, acc0, 0, 0, 0);
    acc1 = __builtin_amdgcn_mfma_f32_32x32x16_bf16(wf1, xf, acc1, 0, 0, 0);
  }

  if (og == 0) {
    // q (prescaled) and k -> tiled fragment layout, mt = n0/32
    ushort* qb = qT + (size_t)(b * 128 + (n0 >> 5)) * 1024;
    ushort* kb = kT + (size_t)(b * 128 + (n0 >> 5)) * 1024;
#pragma unroll
    for (int r = 0; r < 16; ++r) {
      const int i = (r & 3) + 8 * (r >> 2) + 4 * h;  // acc row = channel i
      const size_t off = (size_t)(i >> 4) * 512 + ((i >> 3) & 1) * 256 + 8 * l31 + (i & 7);
      qb[off] = f2bfu((acc0[r] + bq[i]) * SCALE_Q);
      kb[off] = f2bfu(acc1[r] + bk[i]);
    }
  } else {
#pragma unroll
    for (int r = 0; r < 16; ++r) {
      const int rp = (r & 3) + 8 * (r >> 2) + 4 * h;
      const int c0 = (og - 1) * 64 + rp;   // and c1 = c0 + 32
      const int n = n0 + l31;
      const size_t base = (size_t)(b * 256 + (n >> 4)) * 8 * 512;
      const size_t p = ((size_t)((n >> 3) & 1)) * 256 + (n & 7);
      vT[base + (size_t)(c0 >> 5) * 512 + p + 8 * (c0 & 31)] = f2bfu(acc0[r] + bv[c0]);
      vT[base + (size_t)((c0 + 32) >> 5) * 512 + p + 8 * (c0 & 31)] = f2bfu(acc1[r] + bv[c0 + 32]);
    }
  }
}

// ---- flash attention: 4 waves/block, KEY-split, MFMA 32x32x16 bf16 ---------
// grid (B, N/32), block 256. Wave w owns keys [w*1024, (w+1)*1024).
// All fragment loads are contiguous 1KB wave-loads from the tiled layouts.
__global__ __launch_bounds__(256, 2) void flash_mfma(
    const ushort* __restrict__ qT, const ushort* __restrict__ kT,
    const ushort* __restrict__ vT, const float* __restrict__ x,
    const float* __restrict__ gamma, float* __restrict__ out) {
  __shared__ float smem[17152];  // B0[256*33] B1[256*33] ml[128] ll[128]
  float* B0 = smem;
  float* B1 = smem + 8448;
  float* ml = smem + 16896;
  float* ll = smem + 17024;

  const int tid = threadIdx.x;
  const int lane = tid & 63;
  const int w = tid >> 6;
  const int l31 = lane & 31;
  const int h = lane >> 5;
  const int b = blockIdx.x;
  const int n0 = blockIdx.y * 32;
  const int kbase = w * (NN / 4);

  // Q fragments: one 1KB contiguous load each
  const ushort* qb = qT + (size_t)(b * 128 + (n0 >> 5)) * 1024 + lane * 8;
  const bf16x8 qf0 = *reinterpret_cast<const bf16x8*>(qb);
  const bf16x8 qf1 = *reinterpret_cast<const bf16x8*>(qb + 512);

  const ushort* ktb = kT + (size_t)b * 128 * 1024;   // per-batch K tiles
  const ushort* vtb = vT + (size_t)b * 256 * 8 * 512;  // per-batch V tiles

  f32x16 acc[8];
#pragma unroll
  for (int ct = 0; ct < 8; ++ct) acc[ct] = zero16();
  float m_run = -1e30f, l_run = 0.0f;

  for (int m0 = 0; m0 < NN / 4; m0 += 64) {
    const int kabs = kbase + m0;
    // ---- S^T = K^T . Q : 4KB contiguous K ----
    const ushort* kc = ktb + (size_t)(kabs >> 5) * 1024 + lane * 8;
    const bf16x8 kf00 = *reinterpret_cast<const bf16x8*>(kc);
    const bf16x8 kf01 = *reinterpret_cast<const bf16x8*>(kc + 512);
    const bf16x8 kf10 = *reinterpret_cast<const bf16x8*>(kc + 1024);
    const bf16x8 kf11 = *reinterpret_cast<const bf16x8*>(kc + 1536);
    f32x16 st0 = zero16(), st1 = zero16();
    st0 = __builtin_amdgcn_mfma_f32_32x32x16_bf16(kf00, qf0, st0, 0, 0, 0);
    st1 = __builtin_amdgcn_mfma_f32_32x32x16_bf16(kf10, qf0, st1, 0, 0, 0);
    st0 = __builtin_amdgcn_mfma_f32_32x32x16_bf16(kf01, qf1, st0, 0, 0, 0);
    st1 = __builtin_amdgcn_mfma_f32_32x32x16_bf16(kf11, qf1, st1, 0, 0, 0);

    // ---- row max ----
    float t[8];
#pragma unroll
    for (int r = 0; r < 8; ++r)
      t[r] = fmaxf(fmaxf(st0[r], st0[r + 8]), fmaxf(st1[r], st1[r + 8]));
    float mx = fmaxf(fmaxf(fmaxf(t[0], t[1]), fmaxf(t[2], t[3])),
                     fmaxf(fmaxf(t[4], t[5]), fmaxf(t[6], t[7])));
    float ma = mx, mb = mx;
    perm32swap_f(ma, mb);
    const float rowmax = fmaxf(ma, mb);

    // ---- deferred-max online softmax update ----
    if (__any(rowmax > m_run + 8.0f)) {
      const float mnew = fmaxf(m_run, rowmax);
      const float f = exp2f(m_run - mnew);
#pragma unroll
      for (int ct = 0; ct < 8; ++ct)
#pragma unroll
        for (int r = 0; r < 16; ++r) acc[ct][r] *= f;
      l_run *= f;
      m_run = mnew;
    }

    // ---- p = exp2(s - m), row sum ----
#pragma unroll
    for (int r = 0; r < 16; ++r) st0[r] = exp2f(st0[r] - m_run);
#pragma unroll
    for (int r = 0; r < 16; ++r) st1[r] = exp2f(st1[r] - m_run);
    float s8[8];
#pragma unroll
    for (int r = 0; r < 8; ++r)
      s8[r] = (st0[r] + st0[r + 8]) + (st1[r] + st1[r + 8]);
    float ps = ((s8[0] + s8[1]) + (s8[2] + s8[3])) +
               ((s8[4] + s8[5]) + (s8[6] + s8[7]));
    float sa = ps, sb = ps;
    perm32swap_f(sa, sb);
    l_run += sa + sb;

    // ---- P -> bf16 B-fragments (cvt_pk + permlane32_swap) ----
    union PF { int w4[4]; bf16x8 v8; } pf[4];
    {
      int c0 = cvt_pk_bf16(st0[0], st0[1]), c1 = cvt_pk_bf16(st0[2], st0[3]);
      int c2 = cvt_pk_bf16(st0[4], st0[5]), c3 = cvt_pk_bf16(st0[6], st0[7]);
      perm32swap_i(c0, c2); perm32swap_i(c1, c3);
      pf[0].w4[0] = c0; pf[0].w4[1] = c1; pf[0].w4[2] = c2; pf[0].w4[3] = c3;
    }
    {
      int c0 = cvt_pk_bf16(st0[8], st0[9]), c1 = cvt_pk_bf16(st0[10], st0[11]);
      int c2 = cvt_pk_bf16(st0[12], st0[13]), c3 = cvt_pk_bf16(st0[14], st0[15]);
      perm32swap_i(c0, c2); perm32swap_i(c1, c3);
      pf[1].w4[0] = c0; pf[1].w4[1] = c1; pf[1].w4[2] = c2; pf[1].w4[3] = c3;
    }
    {
      int c0 = cvt_pk_bf16(st1[0], st1[1]), c1 = cvt_pk_bf16(st1[2], st1[3]);
      int c2 = cvt_pk_bf16(st1[4], st1[5]), c3 = cvt_pk_bf16(st1[6], st1[7]);
      perm32swap_i(c0, c2); perm32swap_i(c1, c3);
      pf[2].w4[0] = c0; pf[2].w4[1] = c1; pf[2].w4[2] = c2; pf[2].w4[3] = c3;
    }
    {
      int c0 = cvt_pk_bf16(st1[8], st1[9]), c1 = cvt_pk_bf16(st1[10], st1[11]);
      int c2 = cvt_pk_bf16(st1[12], st1[13]), c3 = cvt_pk_bf16(st1[14], st1[15]);
      perm32swap_i(c0, c2); perm32swap_i(c1, c3);
      pf[3].w4[0] = c0; pf[3].w4[1] = c1; pf[3].w4[2] = c2; pf[3].w4[3] = c3;
    }

    // ---- O += V . P^T : 4 k-steps x 8 c-tiles, 32KB contiguous V ----
#pragma unroll
    for (int ksi = 0; ksi < 4; ++ksi) {
      const ushort* vc = vtb + ((size_t)((kabs >> 4) + ksi) * 8) * 512 + lane * 8;
      bf16x8 vf[8];
#pragma unroll
      for (int ct = 0; ct < 8; ++ct)
        vf[ct] = *reinterpret_cast<const bf16x8*>(vc + (size_t)ct * 512);
#pragma unroll
      for (int ct = 0; ct < 8; ++ct)
        acc[ct] = __builtin_amdgcn_mfma_f32_32x32x16_bf16(vf[ct], pf[ksi].v8, acc[ct], 0, 0, 0);
    }
  }

  // ---- flash-decoding combine across the 4 key-chunks (in LDS) ----
  if (h == 0) { ml[w * 32 + l31] = m_run; ll[w * 32 + l31] = l_run; }
  __syncthreads();
  const int q = tid & 31;
  const float m0_ = ml[q], m1_ = ml[32 + q], m2_ = ml[64 + q], m3_ = ml[96 + q];
  const float mt = fmaxf(fmaxf(m0_, m1_), fmaxf(m2_, m3_));
  const float f0 = exp2f(m0_ - mt), f1 = exp2f(m1_ - mt);
  const float f2 = exp2f(m2_ - mt), f3 = exp2f(m3_ - mt);
  const float lt = f0 * ll[q] + f1 * ll[32 + q] + f2 * ll[64 + q] + f3 * ll[96 + q];
  const float fmy = (w == 0) ? f0 : (w == 1) ? f1 : (w == 2) ? f2 : f3;

  if (w < 2) {
    float* Bd = (w == 0) ? B0 : B1;
#pragma unroll
    for (int ct = 0; ct < 8; ++ct)
#pragma unroll
      for (int r = 0; r < 16; ++r) {
        const int c = ct * 32 + (r & 3) + 8 * (r >> 2) + 4 * h;
        Bd[c * 33 + l31] = fmy * acc[ct][r];
      }
  }
  __syncthreads();
  if (w >= 2) {
    float* Bd = (w == 2) ? B0 : B1;
#pragma unroll
    for (int ct = 0; ct < 8; ++ct)
#pragma unroll
      for (int r = 0; r < 16; ++r) {
        const int c = ct * 32 + (r & 3) + 8 * (r >> 2) + 4 * h;
        Bd[c * 33 + l31] += fmy * acc[ct][r];
      }
  }
  __syncthreads();

  // ---- epilogue: out = gamma * O/l + x (coalesced) ----
  const float g = gamma[0];
  const float linv = 1.0f / lt;
#pragma unroll
  for (int rep = 0; rep < 32; ++rep) {
    const int flat = rep * 256 + tid;
    const int c = flat >> 5;
    const float o = B0[c * 33 + q] + B1[c * 33 + q];
    const size_t idx = ((size_t)b * CC + c) * NN + n0 + q;
    out[idx] = g * o * linv + x[idx];
  }
}

extern "C" void kernel_launch(void* const* d_in, const int* in_sizes, int n_in,
                              void* d_out, int out_size, void* d_ws, size_t ws_size,
                              hipStream_t stream) {
  const float* x = (const float*)d_in[0];
  const float* Wq = (const float*)d_in[1];
  const float* bq = (const float*)d_in[2];
  const float* Wk = (const float*)d_in[3];
  const float* bk = (const float*)d_in[4];
  const float* Wv = (const float*)d_in[5];
  const float* bv = (const float*)d_in[6];
  const float* gamma = (const float*)d_in[7];
  float* out = (float*)d_out;

  ushort* qT = (ushort*)d_ws;                       // B*128*2*512
  ushort* kT = qT + (size_t)BB * 128 * 1024;        // B*128*2*512
  ushort* vT = kT + (size_t)BB * 128 * 1024;        // B*256*8*512

  proj_mfma<<<dim3(BB, NN / 32, 5), dim3(64), 0, stream>>>(
      Wq, bq, Wk, bk, Wv, bv, x, qT, kT, vT);
  flash_mfma<<<dim3(BB, NN / 32), dim3(256), 0, stream>>>(
      qT, kT, vT, x, gamma, out);
}

// Round 7
// 80.222 us; speedup vs baseline: 22.4130x; 1.0978x over previous
//
#include <hip/hip_runtime.h>
#include <hip/hip_bf16.h>
#include <cstddef>
#include <cstdint>

#define BB 4
#define CC 256
#define II 32
#define NN 4096

// 1/sqrt(32) * log2(e): fold softmax scale AND exp->exp2 conversion into q.
#define SCALE_Q 0.25505572751402893f

typedef __attribute__((ext_vector_type(8))) short bf16x8;
typedef __attribute__((ext_vector_type(16))) float f32x16;

static __device__ __forceinline__ int cvt_pk_bf16(float lo, float hi) {
  int d;
  asm("v_cvt_pk_bf16_f32 %0, %1, %2" : "=v"(d) : "v"(lo), "v"(hi));
  return d;
}
static __device__ __forceinline__ void perm32swap_i(int& a, int& b) {
  asm("v_permlane32_swap_b32 %0, %1" : "+v"(a), "+v"(b));
}
static __device__ __forceinline__ void perm32swap_f(float& a, float& b) {
  asm("v_permlane32_swap_b32 %0, %1" : "+v"(a), "+v"(b));
}
static __device__ __forceinline__ float max3f(float a, float b, float c) {
  float d;
  asm("v_max3_f32 %0, %1, %2, %3" : "=v"(d) : "v"(a), "v"(b), "v"(c));
  return d;
}
static __device__ __forceinline__ f32x16 zero16() {
  f32x16 z;
#pragma unroll
  for (int i = 0; i < 16; ++i) z[i] = 0.0f;
  return z;
}
static __device__ __forceinline__ bf16x8 pack8(float f0, float f1, float f2,
    float f3, float f4, float f5, float f6, float f7) {
  union { int w[4]; bf16x8 v8; } u;
  u.w[0] = cvt_pk_bf16(f0, f1);
  u.w[1] = cvt_pk_bf16(f2, f3);
  u.w[2] = cvt_pk_bf16(f4, f5);
  u.w[3] = cvt_pk_bf16(f6, f7);
  return u.v8;
}
static __device__ __forceinline__ ushort f2bfu(float f) {
  union { __hip_bfloat16 h; ushort u; } cv;
  cv.h = __float2bfloat16(f);
  return cv.u;
}
static __device__ __forceinline__ int pack4_fp8(float a, float b, float c, float d) {
  int r = __builtin_amdgcn_cvt_pk_fp8_f32(a, b, 0, false);
  r = __builtin_amdgcn_cvt_pk_fp8_f32(c, d, r, true);
  return r;
}
static __device__ __forceinline__ unsigned char f2fp8(float f) {
  return (unsigned char)(__builtin_amdgcn_cvt_pk_fp8_f32(f, f, 0, false) & 0xff);
}

// Layouts:
//  qT/kT (bf16): [b][mt=n/32][frag=i/16][p]; p = 256*((i>>3)&1) + 8*(n&31) + (i&7)
//  vT8  (fp8):   [b][nt=n/16][ct=c/32][p];  p = 256*((n>>3)&1) + 8*(c&31) + (n&7)

// ---- fused qkv projection, MFMA 32x32x16, 1 wave/block ---------------------
// grid (B, N/32, 5): og 0 -> q-tile + k-tile; og 1..4 -> v rows (og-1)*64..+63
__global__ __launch_bounds__(64, 3) void proj_mfma(
    const float* __restrict__ Wq, const float* __restrict__ bq,
    const float* __restrict__ Wk, const float* __restrict__ bk,
    const float* __restrict__ Wv, const float* __restrict__ bv,
    const float* __restrict__ x,
    ushort* __restrict__ qT, ushort* __restrict__ kT,
    unsigned char* __restrict__ vT8) {
  const int lane = threadIdx.x;
  const int l31 = lane & 31;
  const int h = lane >> 5;
  const int b = blockIdx.x;
  const int n0 = blockIdx.y * 32;
  const int og = blockIdx.z;

  const float* xb = x + (size_t)b * CC * NN + n0 + l31;
  const float* wr0 = (og == 0) ? (Wq + (size_t)l31 * CC)
                               : (Wv + (size_t)((og - 1) * 64 + l31) * CC);
  const float* wr1 = (og == 0) ? (Wk + (size_t)l31 * CC)
                               : (Wv + (size_t)((og - 1) * 64 + 32 + l31) * CC);

  f32x16 acc0 = zero16(), acc1 = zero16();
#pragma unroll 4
  for (int ks = 0; ks < 16; ++ks) {
    const int c = ks * 16 + h * 8;
    const float* xp = xb + (size_t)c * NN;
    bf16x8 xf = pack8(xp[0], xp[(size_t)1 * NN], xp[(size_t)2 * NN],
                      xp[(size_t)3 * NN], xp[(size_t)4 * NN], xp[(size_t)5 * NN],
                      xp[(size_t)6 * NN], xp[(size_t)7 * NN]);
    float4 wa = *(const float4*)(wr0 + c);
    float4 wb = *(const float4*)(wr0 + c + 4);
    bf16x8 wf0 = pack8(wa.x, wa.y, wa.z, wa.w, wb.x, wb.y, wb.z, wb.w);
    float4 wc = *(const float4*)(wr1 + c);
    float4 wd = *(const float4*)(wr1 + c + 4);
    bf16x8 wf1 = pack8(wc.x, wc.y, wc.z, wc.w, wd.x, wd.y, wd.z, wd.w);
    acc0 = __builtin_amdgcn_mfma_f32_32x32x16_bf16(wf0, xf, acc0, 0, 0, 0);
    acc1 = __builtin_amdgcn_mfma_f32_32x32x16_bf16(wf1, xf, acc1, 0, 0, 0);
  }

  if (og == 0) {
    ushort* qb = qT + (size_t)(b * 128 + (n0 >> 5)) * 1024;
    ushort* kb = kT + (size_t)(b * 128 + (n0 >> 5)) * 1024;
#pragma unroll
    for (int r = 0; r < 16; ++r) {
      const int i = (r & 3) + 8 * (r >> 2) + 4 * h;
      const size_t off = (size_t)(i >> 4) * 512 + ((i >> 3) & 1) * 256 + 8 * l31 + (i & 7);
      qb[off] = f2bfu((acc0[r] + bq[i]) * SCALE_Q);
      kb[off] = f2bfu(acc1[r] + bk[i]);
    }
  } else {
    const int n = n0 + l31;
    const size_t nbase = (size_t)b * (1 << 20) + (size_t)(n >> 4) * 4096 +
                         ((size_t)((n >> 3) & 1)) * 256 + (n & 7);
#pragma unroll
    for (int r = 0; r < 16; ++r) {
      const int rp = (r & 3) + 8 * (r >> 2) + 4 * h;
      const int c0 = (og - 1) * 64 + rp;
      const int c1 = c0 + 32;
      vT8[nbase + (size_t)(c0 >> 5) * 512 + (c0 & 31) * 8] = f2fp8(acc0[r] + bv[c0]);
      vT8[nbase + (size_t)(c1 >> 5) * 512 + (c1 & 31) * 8] = f2fp8(acc1[r] + bv[c1]);
    }
  }
}

// ---- flash attention: 4 waves/block, KEY-split, XCD-swizzled ---------------
// 1-D grid of 512. xcd = wg&7 owns batch (xcd>>1), n-half (xcd&1):
// per-XCD working set = 1 batch's V(1MB fp8) + K + Q -> L2-resident.
// QK^T bf16 MFMA; PV fp8 MFMA (V and P in e4m3).
__global__ __launch_bounds__(256, 2) void flash_mfma(
    const ushort* __restrict__ qT, const ushort* __restrict__ kT,
    const unsigned char* __restrict__ vT8, const float* __restrict__ x,
    const float* __restrict__ gamma, float* __restrict__ out) {
  __shared__ float smem[17152];  // B0[256*33] B1[256*33] ml[128] ll[128]
  float* B0 = smem;
  float* B1 = smem + 8448;
  float* ml = smem + 16896;
  float* ll = smem + 17024;

  const int tid = threadIdx.x;
  const int lane = tid & 63;
  const int w = tid >> 6;
  const int l31 = lane & 31;
  const int h = lane >> 5;

  const int wg = blockIdx.x;
  const int xcd = wg & 7;
  const int pos = wg >> 3;               // 0..63
  const int b = xcd >> 1;                // 2 XCDs per batch
  const int nt = ((xcd & 1) << 6) + pos; // 0..127
  const int n0 = nt * 32;
  const int kbase = w * (NN / 4);

  const ushort* qb = qT + (size_t)(b * 128 + nt) * 1024 + lane * 8;
  const bf16x8 qf0 = *reinterpret_cast<const bf16x8*>(qb);
  const bf16x8 qf1 = *reinterpret_cast<const bf16x8*>(qb + 512);

  const ushort* ktb = kT + (size_t)b * 128 * 1024;
  const unsigned char* vtb = vT8 + (size_t)b * (1 << 20);

  f32x16 acc[8];
#pragma unroll
  for (int ct = 0; ct < 8; ++ct) acc[ct] = zero16();
  float m_run = -1e30f, l_run = 0.0f;

  for (int m0 = 0; m0 < NN / 4; m0 += 64) {
    const int kabs = kbase + m0;
    // ---- S^T = K^T . Q (bf16) ----
    const ushort* kc = ktb + (size_t)(kabs >> 5) * 1024 + lane * 8;
    const bf16x8 kf00 = *reinterpret_cast<const bf16x8*>(kc);
    const bf16x8 kf01 = *reinterpret_cast<const bf16x8*>(kc + 512);
    const bf16x8 kf10 = *reinterpret_cast<const bf16x8*>(kc + 1024);
    const bf16x8 kf11 = *reinterpret_cast<const bf16x8*>(kc + 1536);
    f32x16 st0 = zero16(), st1 = zero16();
    st0 = __builtin_amdgcn_mfma_f32_32x32x16_bf16(kf00, qf0, st0, 0, 0, 0);
    st1 = __builtin_amdgcn_mfma_f32_32x32x16_bf16(kf10, qf0, st1, 0, 0, 0);
    st0 = __builtin_amdgcn_mfma_f32_32x32x16_bf16(kf01, qf1, st0, 0, 0, 0);
    st1 = __builtin_amdgcn_mfma_f32_32x32x16_bf16(kf11, qf1, st1, 0, 0, 0);

    // ---- row max (v_max3 chains) ----
    float ma_ = max3f(st0[0], st0[1], st0[2]);
    float mb_ = max3f(st0[3], st0[4], st0[5]);
    float mc_ = max3f(st0[6], st0[7], st0[8]);
    float md_ = max3f(st0[9], st0[10], st0[11]);
    ma_ = max3f(st0[12], st0[13], ma_);
    mb_ = max3f(st0[14], st0[15], mb_);
    mc_ = max3f(st1[0], st1[1], mc_);
    md_ = max3f(st1[2], st1[3], md_);
    ma_ = max3f(st1[4], st1[5], ma_);
    mb_ = max3f(st1[6], st1[7], mb_);
    mc_ = max3f(st1[8], st1[9], mc_);
    md_ = max3f(st1[10], st1[11], md_);
    ma_ = max3f(st1[12], st1[13], ma_);
    mb_ = max3f(st1[14], st1[15], mb_);
    float mx = max3f(ma_, mb_, max3f(mc_, md_, -1e30f));
    float sw1 = mx, sw2 = mx;
    perm32swap_f(sw1, sw2);
    const float rowmax = fmaxf(sw1, sw2);

    // ---- deferred-max online softmax update (thr=8 log2 units) ----
    if (__any(rowmax > m_run + 8.0f)) {
      const float mnew = fmaxf(m_run, rowmax);
      const float f = exp2f(m_run - mnew);
#pragma unroll
      for (int ct = 0; ct < 8; ++ct)
#pragma unroll
        for (int r = 0; r < 16; ++r) acc[ct][r] *= f;
      l_run *= f;
      m_run = mnew;
    }

    // ---- p = exp2(s - m), row sum ----
#pragma unroll
    for (int r = 0; r < 16; ++r) st0[r] = exp2f(st0[r] - m_run);
#pragma unroll
    for (int r = 0; r < 16; ++r) st1[r] = exp2f(st1[r] - m_run);
    float s8[8];
#pragma unroll
    for (int r = 0; r < 8; ++r)
      s8[r] = (st0[r] + st0[r + 8]) + (st1[r] + st1[r + 8]);
    float ps = ((s8[0] + s8[1]) + (s8[2] + s8[3])) +
               ((s8[4] + s8[5]) + (s8[6] + s8[7]));
    float sa = ps, sb = ps;
    perm32swap_f(sa, sb);
    l_run += sa + sb;

    // ---- P -> fp8 B-fragments: pack4 + one permlane32_swap per ksi ----
    union LI { int w2[2]; long l; } pf0, pf1, pf2, pf3;
    {
      int A = pack4_fp8(st0[0], st0[1], st0[2], st0[3]);
      int B = pack4_fp8(st0[4], st0[5], st0[6], st0[7]);
      perm32swap_i(A, B);
      pf0.w2[0] = A; pf0.w2[1] = B;
    }
    {
      int A = pack4_fp8(st0[8], st0[9], st0[10], st0[11]);
      int B = pack4_fp8(st0[12], st0[13], st0[14], st0[15]);
      perm32swap_i(A, B);
      pf1.w2[0] = A; pf1.w2[1] = B;
    }
    {
      int A = pack4_fp8(st1[0], st1[1], st1[2], st1[3]);
      int B = pack4_fp8(st1[4], st1[5], st1[6], st1[7]);
      perm32swap_i(A, B);
      pf2.w2[0] = A; pf2.w2[1] = B;
    }
    {
      int A = pack4_fp8(st1[8], st1[9], st1[10], st1[11]);
      int B = pack4_fp8(st1[12], st1[13], st1[14], st1[15]);
      perm32swap_i(A, B);
      pf3.w2[0] = A; pf3.w2[1] = B;
    }
    const long pfl[4] = {pf0.l, pf1.l, pf2.l, pf3.l};

    // ---- O += V . P^T (fp8 MFMA): 4 k-steps x 8 c-tiles ----
#pragma unroll
    for (int ksi = 0; ksi < 4; ++ksi) {
      const unsigned char* vc = vtb + (size_t)((kabs >> 4) + ksi) * 4096 + lane * 8;
#pragma unroll
      for (int ct = 0; ct < 8; ++ct) {
        const long vf = *reinterpret_cast<const long*>(vc + (size_t)ct * 512);
        acc[ct] = __builtin_amdgcn_mfma_f32_32x32x16_fp8_fp8(vf, pfl[ksi], acc[ct], 0, 0, 0);
      }
    }
  }

  // ---- flash-decoding combine across the 4 key-chunks (in LDS) ----
  if (h == 0) { ml[w * 32 + l31] = m_run; ll[w * 32 + l31] = l_run; }
  __syncthreads();
  const int q = tid & 31;
  const float m0_ = ml[q], m1_ = ml[32 + q], m2_ = ml[64 + q], m3_ = ml[96 + q];
  const float mt = fmaxf(fmaxf(m0_, m1_), fmaxf(m2_, m3_));
  const float f0 = exp2f(m0_ - mt), f1 = exp2f(m1_ - mt);
  const float f2 = exp2f(m2_ - mt), f3 = exp2f(m3_ - mt);
  const float lt = f0 * ll[q] + f1 * ll[32 + q] + f2 * ll[64 + q] + f3 * ll[96 + q];
  const float fmy = (w == 0) ? f0 : (w == 1) ? f1 : (w == 2) ? f2 : f3;

  if (w < 2) {
    float* Bd = (w == 0) ? B0 : B1;
#pragma unroll
    for (int ct = 0; ct < 8; ++ct)
#pragma unroll
      for (int r = 0; r < 16; ++r) {
        const int c = ct * 32 + (r & 3) + 8 * (r >> 2) + 4 * h;
        Bd[c * 33 + l31] = fmy * acc[ct][r];
      }
  }
  __syncthreads();
  if (w >= 2) {
    float* Bd = (w == 2) ? B0 : B1;
#pragma unroll
    for (int ct = 0; ct < 8; ++ct)
#pragma unroll
      for (int r = 0; r < 16; ++r) {
        const int c = ct * 32 + (r & 3) + 8 * (r >> 2) + 4 * h;
        Bd[c * 33 + l31] += fmy * acc[ct][r];
      }
  }
  __syncthreads();

  // ---- epilogue: out = gamma * O/l + x (coalesced) ----
  const float g = gamma[0];
  const float linv = 1.0f / lt;
#pragma unroll
  for (int rep = 0; rep < 32; ++rep) {
    const int flat = rep * 256 + tid;
    const int c = flat >> 5;
    const float o = B0[c * 33 + q] + B1[c * 33 + q];
    const size_t idx = ((size_t)b * CC + c) * NN + n0 + q;
    out[idx] = g * o * linv + x[idx];
  }
}

extern "C" void kernel_launch(void* const* d_in, const int* in_sizes, int n_in,
                              void* d_out, int out_size, void* d_ws, size_t ws_size,
                              hipStream_t stream) {
  const float* x = (const float*)d_in[0];
  const float* Wq = (const float*)d_in[1];
  const float* bq = (const float*)d_in[2];
  const float* Wk = (const float*)d_in[3];
  const float* bk = (const float*)d_in[4];
  const float* Wv = (const float*)d_in[5];
  const float* bv = (const float*)d_in[6];
  const float* gamma = (const float*)d_in[7];
  float* out = (float*)d_out;

  ushort* qT = (ushort*)d_ws;                          // B*128*1024 bf16
  ushort* kT = qT + (size_t)BB * 128 * 1024;           // B*128*1024 bf16
  unsigned char* vT8 = (unsigned char*)(kT + (size_t)BB * 128 * 1024);  // B*1MB fp8

  proj_mfma<<<dim3(BB, NN / 32, 5), dim3(64), 0, stream>>>(
      Wq, bq, Wk, bk, Wv, bv, x, qT, kT, vT8);
  flash_mfma<<<dim3(512), dim3(256), 0, stream>>>(
      qT, kT, vT8, x, gamma, out);
}